// Round 1
// baseline (232.492 us; speedup 1.0000x reference)
//
#include <hip/hip_runtime.h>
#include <hip/hip_bf16.h>
#include <stdint.h>

typedef __attribute__((ext_vector_type(8))) short bf16x8;
typedef __attribute__((ext_vector_type(4))) float f32x4;
typedef __attribute__((ext_vector_type(4))) int int4v;

#define MFMA16(a,b,c) __builtin_amdgcn_mfma_f32_16x16x32_bf16((a),(b),(c),0,0,0)

__device__ __forceinline__ unsigned short f2bf(float x) {
  unsigned u = __float_as_uint(x);
  u += 0x7FFFu + ((u >> 16) & 1u);   // round-to-nearest-even
  return (unsigned short)(u >> 16);
}

// ---------------- kernel 1: fp32 -> bf16 for the three activation tensors ----
__global__ __launch_bounds__(256) void conv3_kernel(
    const float* __restrict__ q1, const float* __restrict__ q2,
    const float* __restrict__ kv, unsigned short* __restrict__ out) {
  int idx = blockIdx.x * 256 + threadIdx.x;          // 0 .. 3*2^20-1 (float4 units)
  int seg = idx >> 20;
  int j   = idx & ((1 << 20) - 1);
  const float4* src = (const float4*)(seg == 0 ? q1 : (seg == 1 ? q2 : kv));
  float4 v = src[j];
  ushort4 r;
  r.x = f2bf(v.x); r.y = f2bf(v.y); r.z = f2bf(v.z); r.w = f2bf(v.w);
  ((ushort4*)out)[idx] = r;
}

// ---------------- kernel 2: weights fp32 -> bf16, transposed to [2048][512] --
__global__ __launch_bounds__(256) void convWT_kernel(
    const float* __restrict__ Wq1, const float* __restrict__ Wq2,
    const float* __restrict__ Wkv, unsigned short* __restrict__ WT) {
  __shared__ float tile[32][33];
  int ct = blockIdx.x & 63, kt = blockIdx.x >> 6;
  int tx = threadIdx.x & 31, ty = threadIdx.x >> 5;
  int c = ct * 32;                       // output-column tile base, [0,2048)
  const float* W; int c0; int ldw;
  if (c < 512)       { W = Wq1; c0 = c;        ldw = 512; }
  else if (c < 1024) { W = Wq2; c0 = c - 512;  ldw = 512; }
  else               { W = Wkv; c0 = c - 1024; ldw = 1024; }
#pragma unroll
  for (int rep = 0; rep < 4; ++rep) {
    int k = kt * 32 + ty + rep * 8;
    tile[ty + rep * 8][tx] = W[(size_t)k * ldw + c0 + tx];
  }
  __syncthreads();
#pragma unroll
  for (int rep = 0; rep < 4; ++rep) {
    int cl = ty + rep * 8;
    WT[(size_t)(c + cl) * 512 + kt * 32 + tx] = f2bf(tile[tx][cl]);
  }
}

// ---------------- kernel 3: bf16 GEMM  C[8192][2048] = A @ W -----------------
// N-tiles 0-3: q1@Wq1, 4-7: q2@Wq2, 8-15: kv@Wkv. B given as WT[N][K].
__global__ __launch_bounds__(256) void gemm_kernel(
    const unsigned short* __restrict__ Abf, const unsigned short* __restrict__ WT,
    unsigned short* __restrict__ C) {
  __shared__ unsigned short As[128 * 64];
  __shared__ unsigned short Bs[128 * 64];
  int bn = blockIdx.x & 15, bm = blockIdx.x >> 4;
  int seg = bn >> 2; if (seg > 2) seg = 2;
  const unsigned short* A = Abf + (size_t)seg * 8192 * 512;
  int t = threadIdx.x;
  int l = t & 63, w = t >> 6;
  int i = l & 15, G = l >> 4;
  int wr = w >> 1, wc = w & 1;
  f32x4 acc[4][4];
#pragma unroll
  for (int m = 0; m < 4; ++m)
#pragma unroll
    for (int n = 0; n < 4; ++n) acc[m][n] = (f32x4){0.f, 0.f, 0.f, 0.f};

  for (int k0 = 0; k0 < 512; k0 += 64) {
    __syncthreads();
#pragma unroll
    for (int r2 = 0; r2 < 4; ++r2) {
      int idx = r2 * 256 + t;
      int row = idx >> 3, c8 = (idx & 7) * 8;
      *(int4v*)(&As[row * 64 + c8]) =
          *(const int4v*)(A + (size_t)(bm * 128 + row) * 512 + k0 + c8);
      *(int4v*)(&Bs[row * 64 + c8]) =
          *(const int4v*)(WT + (size_t)(bn * 128 + row) * 512 + k0 + c8);
    }
    __syncthreads();
#pragma unroll
    for (int kk = 0; kk < 2; ++kk) {
      bf16x8 af[4], bfv[4];
#pragma unroll
      for (int m = 0; m < 4; ++m)
        af[m] = *(const bf16x8*)(&As[(wr * 64 + m * 16 + i) * 64 + kk * 32 + G * 8]);
#pragma unroll
      for (int n = 0; n < 4; ++n)
        bfv[n] = *(const bf16x8*)(&Bs[(wc * 64 + n * 16 + i) * 64 + kk * 32 + G * 8]);
#pragma unroll
      for (int m = 0; m < 4; ++m)
#pragma unroll
        for (int n = 0; n < 4; ++n)
          acc[m][n] = MFMA16(af[m], bfv[n], acc[m][n]);
    }
  }
#pragma unroll
  for (int m = 0; m < 4; ++m)
#pragma unroll
    for (int n = 0; n < 4; ++n)
#pragma unroll
      for (int r = 0; r < 4; ++r)
        C[(size_t)(bm * 128 + wr * 64 + m * 16 + G * 4 + r) * 2048 +
          bn * 128 + wc * 64 + n * 16 + i] = f2bf(acc[m][n][r]);
}

// ---------------- kernel 4: V transpose -> Vt[B*H][64][2048] -----------------
__global__ __launch_bounds__(256) void vtT_kernel(
    const unsigned short* __restrict__ C, unsigned short* __restrict__ Vt) {
  __shared__ unsigned short tile[32][33];
  int idx = blockIdx.x;
  int nt = idx & 63, dt = (idx >> 6) & 1, bh = idx >> 7;
  int b = bh >> 3, h = bh & 7;
  int tx = threadIdx.x & 31, ty = threadIdx.x >> 5;
#pragma unroll
  for (int rep = 0; rep < 4; ++rep) {
    int n = nt * 32 + ty + rep * 8;
    tile[ty + rep * 8][tx] =
        C[(size_t)(b * 2048 + n) * 2048 + 1536 + h * 64 + dt * 32 + tx];
  }
  __syncthreads();
#pragma unroll
  for (int rep = 0; rep < 4; ++rep) {
    int dl = ty + rep * 8;
    Vt[((size_t)bh * 64 + dt * 32 + dl) * 2048 + nt * 32 + tx] = tile[tx][dl];
  }
}

// ---------------- kernel 5: flash attention, both branches -------------------
// 512 wgs: qt(8) x h(8) x b(4) x br(2). 4 waves/wg, 64 q-rows/wave, KVBLK=32.
// Swapped QK^T: S^T = mfma(K, Q) so each lane's softmax row (q = rt*16 + lane&15)
// reduces over 8 regs + shfl_xor(16,32). P staged through padded per-wave LDS.
__global__ __launch_bounds__(256, 2) void attn_kernel(
    const unsigned short* __restrict__ C, const unsigned short* __restrict__ Vt,
    float* __restrict__ out) {
  __shared__ unsigned short Plds[4][64][40];   // 40 = 32 + 8 pad (bank spread)
  int bid = blockIdx.x;
  int qt = bid & 7, h = (bid >> 3) & 7, b = (bid >> 6) & 3, br = (bid >> 8) & 1;
  int t = threadIdx.x;
  int l = t & 63, w = t >> 6;
  int i = l & 15, G = l >> 4;
  int qrow0 = qt * 256 + w * 64;
  const unsigned short* Qb = C + (size_t)(b * 2048 + qrow0) * 2048 + br * 512 + h * 64;
  const unsigned short* Kb = C + (size_t)(b * 2048) * 2048 + 1024 + h * 64;
  const unsigned short* Vb = Vt + (size_t)(b * 8 + h) * 64 * 2048;
  float* Ob = out + (size_t)br * (4ull * 2048 * 512) +
              (size_t)(b * 2048 + qrow0) * 512 + h * 64;
  unsigned short (*P)[40] = Plds[w];

  const float C1 = 0.125f * 1.4426950408889634f;   // SCALE * log2(e)

  bf16x8 qf[4][2];
#pragma unroll
  for (int rt = 0; rt < 4; ++rt)
#pragma unroll
    for (int c = 0; c < 2; ++c)
      qf[rt][c] = *(const bf16x8*)(Qb + (size_t)(rt * 16 + i) * 2048 + c * 32 + G * 8);

  f32x4 o[4][4];
  float m2[4], lsum[4];
#pragma unroll
  for (int rt = 0; rt < 4; ++rt) {
    m2[rt] = -INFINITY; lsum[rt] = 0.f;
#pragma unroll
    for (int dt = 0; dt < 4; ++dt) o[rt][dt] = (f32x4){0.f, 0.f, 0.f, 0.f};
  }

  for (int kt = 0; kt < 64; ++kt) {
    const unsigned short* Kt = Kb + (size_t)kt * 32 * 2048;
    bf16x8 kf[2][2];
#pragma unroll
    for (int jt = 0; jt < 2; ++jt)
#pragma unroll
      for (int c = 0; c < 2; ++c)
        kf[jt][c] = *(const bf16x8*)(Kt + (size_t)(jt * 16 + i) * 2048 + c * 32 + G * 8);

    f32x4 s[2][4];
#pragma unroll
    for (int jt = 0; jt < 2; ++jt)
#pragma unroll
      for (int rt = 0; rt < 4; ++rt) {
        s[jt][rt] = MFMA16(kf[jt][0], qf[rt][0], ((f32x4){0.f, 0.f, 0.f, 0.f}));
        s[jt][rt] = MFMA16(kf[jt][1], qf[rt][1], s[jt][rt]);
      }

#pragma unroll
    for (int rt = 0; rt < 4; ++rt) {
      float mx = fmaxf(fmaxf(fmaxf(s[0][rt][0], s[0][rt][1]), fmaxf(s[0][rt][2], s[0][rt][3])),
                       fmaxf(fmaxf(s[1][rt][0], s[1][rt][1]), fmaxf(s[1][rt][2], s[1][rt][3])));
      mx = fmaxf(mx, __shfl_xor(mx, 16));
      mx = fmaxf(mx, __shfl_xor(mx, 32));
      mx *= C1;                                    // base-2 logit units
      if (__any(mx - m2[rt] > 8.0f)) {             // defer-max (T13, THR=8)
        float mnew = fmaxf(m2[rt], mx);
        float al = exp2f(m2[rt] - mnew);
        m2[rt] = mnew;
        lsum[rt] *= al;
        f32x4 av;
        av[0] = __shfl(al, G * 4 + 0);
        av[1] = __shfl(al, G * 4 + 1);
        av[2] = __shfl(al, G * 4 + 2);
        av[3] = __shfl(al, G * 4 + 3);
#pragma unroll
        for (int dt = 0; dt < 4; ++dt) o[rt][dt] *= av;
      }
      float ts = 0.f;
      unsigned pk[4];
#pragma unroll
      for (int jt = 0; jt < 2; ++jt) {
        float p0 = exp2f(s[jt][rt][0] * C1 - m2[rt]);
        float p1 = exp2f(s[jt][rt][1] * C1 - m2[rt]);
        float p2 = exp2f(s[jt][rt][2] * C1 - m2[rt]);
        float p3 = exp2f(s[jt][rt][3] * C1 - m2[rt]);
        ts += (p0 + p1) + (p2 + p3);
        pk[jt * 2 + 0] = (unsigned)f2bf(p0) | ((unsigned)f2bf(p1) << 16);
        pk[jt * 2 + 1] = (unsigned)f2bf(p2) | ((unsigned)f2bf(p3) << 16);
      }
      ts += __shfl_xor(ts, 16);
      ts += __shfl_xor(ts, 32);
      lsum[rt] += ts;
      *(uint2*)(&P[rt * 16 + i][G * 4])      = make_uint2(pk[0], pk[1]);
      *(uint2*)(&P[rt * 16 + i][16 + G * 4]) = make_uint2(pk[2], pk[3]);
    }

    // wave-internal ordering: all lanes' ds_writes complete before ds_reads
    asm volatile("s_waitcnt lgkmcnt(0)" ::: "memory");
    __builtin_amdgcn_sched_barrier(0);

    bf16x8 vf[4];
#pragma unroll
    for (int dt = 0; dt < 4; ++dt)
      vf[dt] = *(const bf16x8*)(Vb + (size_t)(dt * 16 + i) * 2048 + kt * 32 + G * 8);
#pragma unroll
    for (int rt = 0; rt < 4; ++rt) {
      bf16x8 pf = *(const bf16x8*)(&P[rt * 16 + i][G * 8]);
#pragma unroll
      for (int dt = 0; dt < 4; ++dt)
        o[rt][dt] = MFMA16(pf, vf[dt], o[rt][dt]);
    }
  }

#pragma unroll
  for (int rt = 0; rt < 4; ++rt) {
    float inv0 = 1.0f / __shfl(lsum[rt], G * 4 + 0);
    float inv1 = 1.0f / __shfl(lsum[rt], G * 4 + 1);
    float inv2 = 1.0f / __shfl(lsum[rt], G * 4 + 2);
    float inv3 = 1.0f / __shfl(lsum[rt], G * 4 + 3);
#pragma unroll
    for (int dt = 0; dt < 4; ++dt) {
      Ob[(size_t)(rt * 16 + G * 4 + 0) * 512 + dt * 16 + i] = o[rt][dt][0] * inv0;
      Ob[(size_t)(rt * 16 + G * 4 + 1) * 512 + dt * 16 + i] = o[rt][dt][1] * inv1;
      Ob[(size_t)(rt * 16 + G * 4 + 2) * 512 + dt * 16 + i] = o[rt][dt][2] * inv2;
      Ob[(size_t)(rt * 16 + G * 4 + 3) * 512 + dt * 16 + i] = o[rt][dt][3] * inv3;
    }
  }
}

// ---------------- launcher ---------------------------------------------------
extern "C" void kernel_launch(void* const* d_in, const int* in_sizes, int n_in,
                              void* d_out, int out_size, void* d_ws, size_t ws_size,
                              hipStream_t stream) {
  const float* q1  = (const float*)d_in[0];
  const float* q2  = (const float*)d_in[1];
  const float* kv  = (const float*)d_in[2];
  const float* Wq1 = (const float*)d_in[3];
  const float* Wq2 = (const float*)d_in[4];
  const float* Wkv = (const float*)d_in[5];
  float* out = (float*)d_out;
  char* ws = (char*)d_ws;
  // ws layout (bytes): Abf [0, 25165824) -- dead after gemm, reused for Vt
  //                    WT  [25165824, 27262976)
  //                    C   [27262976, 60817408)
  unsigned short* Abf = (unsigned short*)ws;
  unsigned short* WT  = (unsigned short*)(ws + 25165824);
  unsigned short* Cb  = (unsigned short*)(ws + 27262976);
  unsigned short* Vt  = (unsigned short*)ws;   // overlaps Abf (safe: sequential)

  conv3_kernel<<<12288, 256, 0, stream>>>(q1, q2, kv, Abf);
  convWT_kernel<<<1024, 256, 0, stream>>>(Wq1, Wq2, Wkv, WT);
  gemm_kernel<<<1024, 256, 0, stream>>>(Abf, WT, Cb);
  vtT_kernel<<<4096, 256, 0, stream>>>(Cb, Vt);
  attn_kernel<<<512, 256, 0, stream>>>(Cb, Vt, out);
}